// Round 11
// baseline (272.406 us; speedup 1.0000x reference)
//
#include <hip/hip_runtime.h>
#include <hip/hip_bf16.h>

#define NTOK 4096   // B*T
#define DDIM 1024
#define NEXP 8
#define FDIM 2048
#define CAP  4096   // max assignments per expert (list storage)
#define RTOK 16     // tokens per router block
#define MT   16     // m-tiles per expert (2048-row capacity)

typedef float f32x4 __attribute__((ext_vector_type(4)));
typedef short s16x8 __attribute__((ext_vector_type(8)));
typedef short s16x4 __attribute__((ext_vector_type(4)));

__device__ __forceinline__ unsigned short f2bf(float f) {
  unsigned int u = __float_as_uint(f);
  unsigned int r = u + 0x7fffu + ((u >> 16) & 1u);
  return (unsigned short)(r >> 16);
}

__device__ __forceinline__ void gload16(const void* g, void* l) {
  __builtin_amdgcn_global_load_lds(
      (__attribute__((address_space(1))) unsigned int*)(g),
      (__attribute__((address_space(3))) unsigned int*)(l), 16, 0, 0);
}

// ---------------- transpose+cast: src [E][R][C] f32 -> dst [E][C][R] bf16 ----------------
__global__ __launch_bounds__(256)
void k_transpose_cast(const float* __restrict__ src, unsigned short* __restrict__ dst,
                      int R, int C) {
  __shared__ float tile[64][68];   // pad 4 -> read-phase banks distinct
  const int e = blockIdx.z;
  const int c0 = blockIdx.x * 64, r0 = blockIdx.y * 64;
  const float* s = src + (size_t)e * R * C;
  unsigned short* d = dst + (size_t)e * R * C;
  const int tid = threadIdx.x;
  const int lr = tid >> 4, lc = (tid & 15) * 4;     // load: 16 rows/pass, 4 passes
  #pragma unroll
  for (int p = 0; p < 4; p++) {
    float4 v = *(const float4*)(s + (size_t)(r0 + p * 16 + lr) * C + c0 + lc);
    tile[p * 16 + lr][lc]     = v.x;
    tile[p * 16 + lr][lc + 1] = v.y;
    tile[p * 16 + lr][lc + 2] = v.z;
    tile[p * 16 + lr][lc + 3] = v.w;
  }
  __syncthreads();
  const int sc = tid >> 3, sr = (tid & 7) * 8;      // store: 32 cols/pass, 2 passes
  #pragma unroll
  for (int p = 0; p < 2; p++) {
    int c = p * 32 + sc;
    s16x8 o;
    #pragma unroll
    for (int j = 0; j < 8; j++) o[j] = (short)f2bf(tile[sr + j][c]);
    *(s16x8*)(d + (size_t)(c0 + c) * R + r0 + sr) = o;   // 16B coalesced
  }
}

// ---------------- router: LDS-tiled, thread=(token,expert), fp64 accum; also emits xb (bf16 x) ----------------
__global__ __launch_bounds__(128)
void k_router(const float* __restrict__ x, const float* __restrict__ gw,
              unsigned short* __restrict__ xb,
              float* __restrict__ topw, int* __restrict__ elist,
              int* __restrict__ ecnt, int* __restrict__ cnt1,
              float* __restrict__ psum, float* __restrict__ sqsum) {
  __shared__ float gwt[NEXP][DDIM + 4];   // gw transposed [e][d], pad -> conflict-free b128
  __shared__ float xs[RTOK][264];         // x chunk [tok][256 cols], pad 8 -> <=2-way
  __shared__ double lgd[RTOK][NEXP];
  __shared__ float bps[NEXP];
  __shared__ int bc[NEXP];
  __shared__ float bsq;
  const int tid = threadIdx.x;
  const int tok0 = blockIdx.x * RTOK;

  for (int i = tid; i < DDIM * NEXP; i += 128) {
    int d = i >> 3, e = i & 7;
    gwt[e][d] = gw[i];
  }
  if (tid < NEXP) { bps[tid] = 0.f; bc[tid] = 0; }
  if (tid == 0) bsq = 0.f;

  const int t = tid >> 3, e = tid & 7;    // token-in-block, expert
  double a0 = 0.0, a1 = 0.0, a2 = 0.0, a3 = 0.0;
  for (int c = 0; c < DDIM; c += 256) {
    __syncthreads();
    for (int i = tid; i < RTOK * 64; i += 128) {
      int r = i >> 6, c4 = i & 63;
      float4 v = *(const float4*)(x + (size_t)(tok0 + r) * DDIM + c + c4 * 4);
      *(float4*)&xs[r][c4 * 4] = v;
      s16x4 o;
      o[0] = (short)f2bf(v.x); o[1] = (short)f2bf(v.y);
      o[2] = (short)f2bf(v.z); o[3] = (short)f2bf(v.w);
      *(s16x4*)(xb + (size_t)(tok0 + r) * DDIM + c + c4 * 4) = o;
    }
    __syncthreads();
    #pragma unroll 8
    for (int d4 = 0; d4 < 64; d4++) {
      float4 xv = *(const float4*)&xs[t][d4 * 4];
      float4 gv = *(const float4*)&gwt[e][c + d4 * 4];
      a0 += (double)xv.x * (double)gv.x;
      a1 += (double)xv.y * (double)gv.y;
      a2 += (double)xv.z * (double)gv.z;
      a3 += (double)xv.w * (double)gv.w;
    }
  }
  lgd[t][e] = (a0 + a1) + (a2 + a3);
  __syncthreads();

  if (tid < RTOK) {
    int tok = tok0 + tid;
    double acc[NEXP];
    #pragma unroll
    for (int k = 0; k < NEXP; k++) acc[k] = lgd[tid][k];
    int i0 = 0; double v0 = acc[0];
    #pragma unroll
    for (int k = 1; k < NEXP; k++) if (acc[k] > v0) { v0 = acc[k]; i0 = k; }
    int i1 = (i0 == 0) ? 1 : 0; double v1 = acc[i1];
    #pragma unroll
    for (int k = 0; k < NEXP; k++) if (k != i0 && acc[k] > v1) { v1 = acc[k]; i1 = k; }
    float w0 = 1.0f / (1.0f + expf((float)(v1 - v0)));   // softmax([v0,v1])[0]
    topw[2*tok] = w0; topw[2*tok + 1] = 1.0f - w0;
    int s0 = atomicAdd(&ecnt[i0], 1); elist[i0*CAP + s0] = 2*tok;
    int s1 = atomicAdd(&ecnt[i1], 1); elist[i1*CAP + s1] = 2*tok + 1;
    atomicAdd(&bc[i0], 1);
    float lm = (float)acc[0];
    #pragma unroll
    for (int k = 1; k < NEXP; k++) lm = fmaxf(lm, (float)acc[k]);
    float pe[NEXP], ps = 0.f, sq = 0.f;
    #pragma unroll
    for (int k = 0; k < NEXP; k++) {
      float le = (float)acc[k];
      pe[k] = expf(le - lm); ps += pe[k];
      sq += le * le;
    }
    float inv = 1.0f / ps;
    #pragma unroll
    for (int k = 0; k < NEXP; k++) atomicAdd(&bps[k], pe[k] * inv);
    atomicAdd(&bsq, sq);
  }
  __syncthreads();
  if (tid < NEXP) { atomicAdd(&psum[tid], bps[tid]); atomicAdd(&cnt1[tid], bc[tid]); }
  if (tid == 0) atomicAdd(sqsum, bsq);
}

// ---------------- grouped GEMM: 128x128 tile, BK=128, 4 waves (wave 64x64), gload_lds ----------------
// Per-wave 64x64 (MF=NF=4): LDS reads/FLOP cut 1.5x vs 8-wave 64x32 (R7/R9).
// 1D grid + XCD-chunked swizzle; row = 128 bf16 = 256 B; swizzle: 16B-col ^= (row & 15).
// GEMM1: A=xb (row=aid>>1), K=1024, N=2048, out=H bf16 bias+gelu
// GEMM2: A=H  (row=aid),    K=2048, N=1024, out=obuf f32 bias
template<int K, int N, bool GELU, bool ROWSHIFT>
__global__ __launch_bounds__(256)
void k_gemm(const unsigned short* __restrict__ A, const unsigned short* __restrict__ Bt,
            const float* __restrict__ bias, void* __restrict__ Out,
            const int* __restrict__ elist, const int* __restrict__ ecnt) {
  constexpr int BM = 128, BN = 128, BK = 128;
  constexpr int GX = N / BN;             // n-tiles per expert
  constexpr int TOT = GX * MT * NEXP;
  constexpr int CHUNK = TOT / 8;         // one expert's tile set
  constexpr int AISS = 8;                // 256 thr x 16B = 16 rows x 256B per issue
  constexpr int BISS = 8;
  constexpr int MF = 4, NF = 4;          // per-wave 64x64
  __shared__ unsigned char lsA[BM * 256];   // 32 KB, XOR-16 swizzled
  __shared__ unsigned char lsB[BN * 256];   // 32 KB

  // XCD-chunked bijective swizzle (TOT % 8 == 0)
  const int w = blockIdx.x;
  const int swz = (w & 7) * CHUNK + (w >> 3);
  const int e = swz / (GX * MT);
  const int loc = swz % (GX * MT);
  const int mt = loc % MT, nt = loc / MT;   // mt fastest: co-resident blocks share B panel

  const int cnt = ecnt[e];
  const int m0 = mt * BM;
  if (m0 >= cnt) return;
  const int rv = min(BM, cnt - m0);
  const int* lst = elist + e * CAP + m0;
  const int tid = threadIdx.x, wv = tid >> 6, lane = tid & 63;
  const int wm = wv >> 1, wn = wv & 1;   // 2x2 wave grid, wave owns 64x64
  const unsigned short* Be = Bt + (size_t)e * N * K;

  // staging: issue li covers rows li*16 + (tid>>4); 16B unit cu = tid&15
  // src col16 = cu ^ (r&15) (pre-swizzled global source; LDS dest lane-linear — rule #21)
  const unsigned short* agp[AISS];
  const unsigned short* bgp[BISS];
  int adst[AISS], bdst[BISS];
  const int cu = tid & 15;
  #pragma unroll
  for (int li = 0; li < AISS; li++) {
    int r = li * 16 + (tid >> 4);
    int rr = (r < rv) ? r : 0;           // clamp padded rows to a valid list entry
    int aid = lst[rr];
    int arow = ROWSHIFT ? (aid >> 1) : aid;
    int csrc = (cu ^ (r & 15)) * 16;     // byte offset in row
    agp[li] = A + (size_t)arow * K + (csrc >> 1);
    adst[li] = r * 256 + cu * 16;        // lane-linear dest
  }
  #pragma unroll
  for (int li = 0; li < BISS; li++) {
    int r = li * 16 + (tid >> 4);
    int csrc = (cu ^ (r & 15)) * 16;
    bgp[li] = Be + (size_t)(nt * BN + r) * K + (csrc >> 1);
    bdst[li] = r * 256 + cu * 16;
  }

  f32x4 acc[MF][NF];
  #pragma unroll
  for (int mi = 0; mi < MF; mi++)
    #pragma unroll
    for (int ni = 0; ni < NF; ni++)
      acc[mi][ni] = (f32x4){0.f, 0.f, 0.f, 0.f};

  constexpr int NK = K / BK;
  for (int t = 0; t < NK; ++t) {
    const int k0 = t * BK;
    #pragma unroll
    for (int li = 0; li < AISS; li++) gload16(agp[li] + k0, &lsA[adst[li]]);
    #pragma unroll
    for (int li = 0; li < BISS; li++) gload16(bgp[li] + k0, &lsB[bdst[li]]);
    __syncthreads();                     // drains vmcnt, publishes LDS
    #pragma unroll
    for (int ks = 0; ks < 4; ks++) {     // 4 k-slices of 32 within BK=128
      s16x8 af[MF], bf[NF];
      #pragma unroll
      for (int mi = 0; mi < MF; mi++) {
        int row = wm * 64 + mi * 16 + (lane & 15);
        int c16 = (ks * 4 + (lane >> 4)) ^ (row & 15);
        af[mi] = *(const s16x8*)&lsA[row * 256 + c16 * 16];
      }
      #pragma unroll
      for (int ni = 0; ni < NF; ni++) {
        int row = wn * 64 + ni * 16 + (lane & 15);
        int c16 = (ks * 4 + (lane >> 4)) ^ (row & 15);
        bf[ni] = *(const s16x8*)&lsB[row * 256 + c16 * 16];
      }
      #pragma unroll
      for (int mi = 0; mi < MF; mi++)
        #pragma unroll
        for (int ni = 0; ni < NF; ni++)
          acc[mi][ni] = __builtin_amdgcn_mfma_f32_16x16x32_bf16(af[mi], bf[ni], acc[mi][ni], 0, 0, 0);
    }
    __syncthreads();                     // all reads done before next stage overwrites
  }

  // epilogue: C/D layout col=lane&15, row=4*(lane>>4)+reg (verified m89/m91)
  const int g4 = (lane >> 4) * 4, cn = lane & 15;
  #pragma unroll
  for (int mi = 0; mi < MF; mi++) {
    #pragma unroll
    for (int reg = 0; reg < 4; reg++) {
      int r = wm * 64 + mi * 16 + g4 + reg;
      if (r < rv) {
        int aid = lst[r];
        #pragma unroll
        for (int ni = 0; ni < NF; ni++) {
          int n = nt * BN + wn * 64 + ni * 16 + cn;
          float v = acc[mi][ni][reg] + bias[(size_t)e * N + n];
          if constexpr (GELU) {
            v = 0.5f * v * (1.0f + erff(v * 0.70710678118654752f));  // exact gelu
            ((unsigned short*)Out)[(size_t)aid * N + n] = f2bf(v);
          } else {
            ((float*)Out)[(size_t)aid * N + n] = v;
          }
        }
      }
    }
  }
}

// ---------------- combine top-2 rows (+ fused aux-loss finalize) ----------------
__global__ void k_combine(const float* __restrict__ buf, const float* __restrict__ topw,
                          float* __restrict__ out,
                          const int* __restrict__ cnt1, const float* __restrict__ psum,
                          const float* __restrict__ sqsum) {
  int i = blockIdx.x * 256 + threadIdx.x;          // per float4, NTOK*DDIM/4 total
  int t = i >> 8, c = i & 255;                     // DDIM/4 = 256
  float w0 = topw[2*t], w1 = topw[2*t + 1];
  float4 a = ((const float4*)(buf + (size_t)(2*t) * DDIM))[c];
  float4 b = ((const float4*)(buf + (size_t)(2*t + 1) * DDIM))[c];
  float4 o;
  o.x = w0*a.x + w1*b.x; o.y = w0*a.y + w1*b.y;
  o.z = w0*a.z + w1*b.z; o.w = w0*a.w + w1*b.w;
  ((float4*)out)[i] = o;
  if (i == 0) {
    float s = 0.f;
    for (int e = 0; e < NEXP; e++)
      s += ((float)cnt1[e] / (float)NTOK) * (psum[e] / (float)NTOK);
    out[(size_t)NTOK * DDIM] = (float)NEXP * s + (*sqsum) / (float)(NTOK * NEXP) * 1e-3f;
  }
}

extern "C" void kernel_launch(void* const* d_in, const int* in_sizes, int n_in,
                              void* d_out, int out_size, void* d_ws, size_t ws_size,
                              hipStream_t stream) {
  const float* x  = (const float*)d_in[0];
  const float* gw = (const float*)d_in[1];
  const float* w1 = (const float*)d_in[2];
  const float* b1 = (const float*)d_in[3];
  const float* w2 = (const float*)d_in[4];
  const float* b2 = (const float*)d_in[5];
  float* out = (float*)d_out;
  char* p = (char*)d_ws;

  // workspace layout (~136 MB)
  int*   ecnt  = (int*)p;                    // [8]
  int*   cnt1  = (int*)(p + 32);             // [8]
  float* psum  = (float*)(p + 64);           // [8]
  float* sqsum = (float*)(p + 96);           // [1]
  float* topw  = (float*)(p + 256);                            // 32 KB
  int*   elist = (int*)(p + 256 + 32768);                      // 128 KB
  unsigned short* xb  = (unsigned short*)(p + 256 + 32768 + 131072);   // 8 MB
  unsigned short* w1t = xb  + (size_t)NTOK * DDIM;                     // 32 MB  [E][F][D]
  unsigned short* w2t = w1t + (size_t)NEXP * DDIM * FDIM;              // 32 MB  [E][D][F]
  unsigned short* Hb  = w2t + (size_t)NEXP * DDIM * FDIM;              // 32 MB  [8192][F]
  float* obuf = (float*)(Hb + (size_t)NTOK * 2 * FDIM);                // 32 MB  [8192][D]

  hipMemsetAsync(p, 0, 128, stream);
  k_transpose_cast<<<dim3(FDIM/64, DDIM/64, NEXP), 256, 0, stream>>>(w1, w1t, DDIM, FDIM);
  k_transpose_cast<<<dim3(DDIM/64, FDIM/64, NEXP), 256, 0, stream>>>(w2, w2t, FDIM, DDIM);
  k_router<<<NTOK / RTOK, 128, 0, stream>>>(x, gw, xb, topw, elist, ecnt, cnt1, psum, sqsum);
  // 1D swizzled grids: GEMM1 16nt*16mt*8e=2048 blocks; GEMM2 8nt*16mt*8e=1024 blocks
  k_gemm<DDIM, FDIM, true,  true ><<<(FDIM/128)*MT*NEXP, 256, 0, stream>>>(xb, w1t, b1, Hb, elist, ecnt);
  k_gemm<FDIM, DDIM, false, false><<<(DDIM/128)*MT*NEXP, 256, 0, stream>>>(Hb, w2t, b2, obuf, elist, ecnt);
  k_combine<<<NTOK * DDIM / 4 / 256, 256, 0, stream>>>(obuf, topw, out, cnt1, psum, sqsum);
}

// Round 12
// 249.236 us; speedup vs baseline: 1.0930x; 1.0930x over previous
//
#include <hip/hip_runtime.h>
#include <hip/hip_bf16.h>

#define NTOK 4096   // B*T
#define DDIM 1024
#define NEXP 8
#define FDIM 2048
#define CAP  4096   // max assignments per expert (list storage)
#define RTOK 32     // tokens per router block (256 threads)
#define MT   16     // m-tiles per expert (2048-row capacity)

typedef float f32x4 __attribute__((ext_vector_type(4)));
typedef short s16x8 __attribute__((ext_vector_type(8)));
typedef short s16x4 __attribute__((ext_vector_type(4)));

__device__ __forceinline__ unsigned short f2bf(float f) {
  unsigned int u = __float_as_uint(f);
  unsigned int r = u + 0x7fffu + ((u >> 16) & 1u);
  return (unsigned short)(r >> 16);
}

__device__ __forceinline__ void gload16(const void* g, void* l) {
  __builtin_amdgcn_global_load_lds(
      (__attribute__((address_space(1))) unsigned int*)(g),
      (__attribute__((address_space(3))) unsigned int*)(l), 16, 0, 0);
}

// ================= fused prep: w1 transpose | w2 transpose | router =================
// 1D grid, 256 threads. Blocks [0,4096): w1t; [4096,8192): w2t; [8192,8320): router.
// All three are independent memory-bound jobs — fusing overlaps their HBM traffic.
__device__ __forceinline__ void transpose_tile(const float* __restrict__ src,
                                               unsigned short* __restrict__ dst,
                                               int R, int C, int c0, int r0, int e,
                                               char* smem, int tid) {
  float (*tile)[68] = (float(*)[68])smem;   // pad 4 -> read-phase banks distinct
  const float* s = src + (size_t)e * R * C;
  unsigned short* d = dst + (size_t)e * R * C;
  const int lr = tid >> 4, lc = (tid & 15) * 4;     // load: 16 rows/pass, 4 passes
  #pragma unroll
  for (int p = 0; p < 4; p++) {
    float4 v = *(const float4*)(s + (size_t)(r0 + p * 16 + lr) * C + c0 + lc);
    tile[p * 16 + lr][lc]     = v.x;
    tile[p * 16 + lr][lc + 1] = v.y;
    tile[p * 16 + lr][lc + 2] = v.z;
    tile[p * 16 + lr][lc + 3] = v.w;
  }
  __syncthreads();
  const int sc = tid >> 3, sr = (tid & 7) * 8;      // store: 32 cols/pass, 2 passes
  #pragma unroll
  for (int p = 0; p < 2; p++) {
    int c = p * 32 + sc;
    s16x8 o;
    #pragma unroll
    for (int j = 0; j < 8; j++) o[j] = (short)f2bf(tile[sr + j][c]);
    *(s16x8*)(d + (size_t)(c0 + c) * R + r0 + sr) = o;   // 16B coalesced
  }
}

__global__ __launch_bounds__(256)
void k_prep(const float* __restrict__ x, const float* __restrict__ gw,
            const float* __restrict__ w1, const float* __restrict__ w2,
            unsigned short* __restrict__ xb, unsigned short* __restrict__ w1t,
            unsigned short* __restrict__ w2t,
            float* __restrict__ topw, int* __restrict__ elist,
            int* __restrict__ ecnt, int* __restrict__ cnt1,
            float* __restrict__ psum, float* __restrict__ sqsum) {
  __shared__ char smem[68864];
  const int bid = blockIdx.x, tid = threadIdx.x;

  if (bid < 4096) {          // w1 [E][1024][2048] -> w1t [E][2048][1024]
    int cx = bid & 31, ry = (bid >> 5) & 15, e = bid >> 9;
    transpose_tile(w1, w1t, DDIM, FDIM, cx * 64, ry * 64, e, smem, tid);
    return;
  }
  if (bid < 8192) {          // w2 [E][2048][1024] -> w2t [E][1024][2048]
    int b = bid - 4096;
    int cx = b & 15, ry = (b >> 4) & 31, e = b >> 9;
    transpose_tile(w2, w2t, FDIM, DDIM, cx * 64, ry * 64, e, smem, tid);
    return;
  }

  // ---- router: 128 blocks x 32 tokens; thread=(token,expert); fp64 accum; emits xb ----
  float (*gwt)[DDIM + 4] = (float(*)[DDIM + 4])smem;          // 32896 B
  float (*xs)[264]       = (float(*)[264])(smem + 32896);     // 33792 B
  double (*lgd)[NEXP]    = (double(*)[NEXP])(smem + 66688);   // 2048 B
  float* bps = (float*)(smem + 68736);
  int*   bc  = (int*)(smem + 68768);
  float* bsq = (float*)(smem + 68800);
  const int tok0 = (bid - 8192) * RTOK;

  for (int i = tid; i < DDIM * NEXP; i += 256) {
    int d = i >> 3, e = i & 7;
    gwt[e][d] = gw[i];
  }
  if (tid < NEXP) { bps[tid] = 0.f; bc[tid] = 0; }
  if (tid == 0) *bsq = 0.f;

  const int t = tid >> 3, e = tid & 7;    // token-in-block, expert
  double a0 = 0.0, a1 = 0.0, a2 = 0.0, a3 = 0.0;
  for (int c = 0; c < DDIM; c += 256) {
    __syncthreads();
    for (int i = tid; i < RTOK * 64; i += 256) {   // [32][256] chunk, float4 coalesced
      int r = i >> 6, c4 = i & 63;
      float4 v = *(const float4*)(x + (size_t)(tok0 + r) * DDIM + c + c4 * 4);
      *(float4*)&xs[r][c4 * 4] = v;
      s16x4 o;
      o[0] = (short)f2bf(v.x); o[1] = (short)f2bf(v.y);
      o[2] = (short)f2bf(v.z); o[3] = (short)f2bf(v.w);
      *(s16x4*)(xb + (size_t)(tok0 + r) * DDIM + c + c4 * 4) = o;
    }
    __syncthreads();
    #pragma unroll 8
    for (int d4 = 0; d4 < 64; d4++) {
      float4 xv = *(const float4*)&xs[t][d4 * 4];
      float4 gv = *(const float4*)&gwt[e][c + d4 * 4];
      a0 += (double)xv.x * (double)gv.x;
      a1 += (double)xv.y * (double)gv.y;
      a2 += (double)xv.z * (double)gv.z;
      a3 += (double)xv.w * (double)gv.w;
    }
  }
  lgd[t][e] = (a0 + a1) + (a2 + a3);
  __syncthreads();

  if (tid < RTOK) {
    int tok = tok0 + tid;
    double acc[NEXP];
    #pragma unroll
    for (int k = 0; k < NEXP; k++) acc[k] = lgd[tid][k];
    int i0 = 0; double v0 = acc[0];
    #pragma unroll
    for (int k = 1; k < NEXP; k++) if (acc[k] > v0) { v0 = acc[k]; i0 = k; }
    int i1 = (i0 == 0) ? 1 : 0; double v1 = acc[i1];
    #pragma unroll
    for (int k = 0; k < NEXP; k++) if (k != i0 && acc[k] > v1) { v1 = acc[k]; i1 = k; }
    float w0 = 1.0f / (1.0f + expf((float)(v1 - v0)));   // softmax([v0,v1])[0]
    topw[2*tok] = w0; topw[2*tok + 1] = 1.0f - w0;
    int s0 = atomicAdd(&ecnt[i0], 1); elist[i0*CAP + s0] = 2*tok;
    int s1 = atomicAdd(&ecnt[i1], 1); elist[i1*CAP + s1] = 2*tok + 1;
    atomicAdd(&bc[i0], 1);
    float lm = (float)acc[0];
    #pragma unroll
    for (int k = 1; k < NEXP; k++) lm = fmaxf(lm, (float)acc[k]);
    float pe[NEXP], ps = 0.f, sq = 0.f;
    #pragma unroll
    for (int k = 0; k < NEXP; k++) {
      float le = (float)acc[k];
      pe[k] = expf(le - lm); ps += pe[k];
      sq += le * le;
    }
    float inv = 1.0f / ps;
    #pragma unroll
    for (int k = 0; k < NEXP; k++) atomicAdd(&bps[k], pe[k] * inv);
    atomicAdd(bsq, sq);
  }
  __syncthreads();
  if (tid < NEXP) { atomicAdd(&psum[tid], bps[tid]); atomicAdd(&cnt1[tid], bc[tid]); }
  if (tid == 0) atomicAdd(sqsum, *bsq);
}

// ---------------- grouped GEMM (R9-proven): 128x128 tile, BK=128, 8 waves, gload_lds ----------------
// 1D grid + XCD-chunked swizzle; row = 128 bf16 = 256 B; swizzle: 16B-col ^= (row & 15).
// GEMM1: A=xb (row=aid>>1), K=1024, N=2048, out=H bf16 bias+gelu
// GEMM2: A=H  (row=aid),    K=2048, N=1024, out=obuf f32 bias
template<int K, int N, bool GELU, bool ROWSHIFT>
__global__ __launch_bounds__(512)
void k_gemm(const unsigned short* __restrict__ A, const unsigned short* __restrict__ Bt,
            const float* __restrict__ bias, void* __restrict__ Out,
            const int* __restrict__ elist, const int* __restrict__ ecnt) {
  constexpr int BM = 128, BN = 128, BK = 128, WM = 2, WN = 4;
  constexpr int GX = N / BN;             // n-tiles per expert
  constexpr int TOT = GX * MT * NEXP;
  constexpr int CHUNK = TOT / 8;         // one expert's tile set
  constexpr int AISS = BM / 32;          // 4  (512 thr x 16B cover 32 rows x 256B per issue)
  constexpr int BISS = BN / 32;          // 4
  constexpr int MF = BM / WM / 16;       // 4
  constexpr int NF = BN / WN / 16;       // 2
  __shared__ unsigned char lsA[BM * 256];   // 32 KB, XOR-16 swizzled
  __shared__ unsigned char lsB[BN * 256];   // 32 KB

  // XCD-chunked bijective swizzle (TOT % 8 == 0)
  const int w = blockIdx.x;
  const int swz = (w & 7) * CHUNK + (w >> 3);
  const int e = swz / (GX * MT);
  const int loc = swz % (GX * MT);
  const int mt = loc % MT, nt = loc / MT;   // mt fastest: co-resident blocks share B panel

  const int cnt = ecnt[e];
  const int m0 = mt * BM;
  if (m0 >= cnt) return;
  const int rv = min(BM, cnt - m0);
  const int* lst = elist + e * CAP + m0;
  const int tid = threadIdx.x, wv = tid >> 6, lane = tid & 63;
  const int wm = wv / WN, wn = wv % WN;
  const unsigned short* Be = Bt + (size_t)e * N * K;

  // staging: thread covers row r = li*32 + (tid>>4), 16B unit cu = tid&15
  // src col16 = cu ^ (r&15)  (pre-swizzled global source; LDS dest lane-linear — rule #21)
  const unsigned short* agp[AISS];
  const unsigned short* bgp[BISS];
  int adst[AISS], bdst[BISS];
  const int cu = tid & 15;
  #pragma unroll
  for (int li = 0; li < AISS; li++) {
    int r = li * 32 + (tid >> 4);
    int rr = (r < rv) ? r : 0;           // clamp padded rows to a valid list entry
    int aid = lst[rr];
    int arow = ROWSHIFT ? (aid >> 1) : aid;
    int csrc = (cu ^ (r & 15)) * 16;     // byte offset in row
    agp[li] = A + (size_t)arow * K + (csrc >> 1);
    adst[li] = r * 256 + cu * 16;        // lane-linear dest
  }
  #pragma unroll
  for (int li = 0; li < BISS; li++) {
    int r = li * 32 + (tid >> 4);
    int csrc = (cu ^ (r & 15)) * 16;
    bgp[li] = Be + (size_t)(nt * BN + r) * K + (csrc >> 1);
    bdst[li] = r * 256 + cu * 16;
  }

  f32x4 acc[MF][NF];
  #pragma unroll
  for (int mi = 0; mi < MF; mi++)
    #pragma unroll
    for (int ni = 0; ni < NF; ni++)
      acc[mi][ni] = (f32x4){0.f, 0.f, 0.f, 0.f};

  constexpr int NK = K / BK;
  for (int t = 0; t < NK; ++t) {
    const int k0 = t * BK;
    #pragma unroll
    for (int li = 0; li < AISS; li++) gload16(agp[li] + k0, &lsA[adst[li]]);
    #pragma unroll
    for (int li = 0; li < BISS; li++) gload16(bgp[li] + k0, &lsB[bdst[li]]);
    __syncthreads();                     // drains vmcnt, publishes LDS
    #pragma unroll
    for (int ks = 0; ks < 4; ks++) {     // 4 k-slices of 32 within BK=128
      s16x8 af[MF], bf[NF];
      #pragma unroll
      for (int mi = 0; mi < MF; mi++) {
        int row = wm * (BM / WM) + mi * 16 + (lane & 15);
        int c16 = (ks * 4 + (lane >> 4)) ^ (row & 15);
        af[mi] = *(const s16x8*)&lsA[row * 256 + c16 * 16];
      }
      #pragma unroll
      for (int ni = 0; ni < NF; ni++) {
        int row = wn * (BN / WN) + ni * 16 + (lane & 15);
        int c16 = (ks * 4 + (lane >> 4)) ^ (row & 15);
        bf[ni] = *(const s16x8*)&lsB[row * 256 + c16 * 16];
      }
      #pragma unroll
      for (int mi = 0; mi < MF; mi++)
        #pragma unroll
        for (int ni = 0; ni < NF; ni++)
          acc[mi][ni] = __builtin_amdgcn_mfma_f32_16x16x32_bf16(af[mi], bf[ni], acc[mi][ni], 0, 0, 0);
    }
    __syncthreads();                     // all reads done before next stage overwrites
  }

  // epilogue: C/D layout col=lane&15, row=4*(lane>>4)+reg (verified m89/m91)
  const int g4 = (lane >> 4) * 4, cn = lane & 15;
  #pragma unroll
  for (int mi = 0; mi < MF; mi++) {
    #pragma unroll
    for (int reg = 0; reg < 4; reg++) {
      int r = wm * (BM / WM) + mi * 16 + g4 + reg;
      if (r < rv) {
        int aid = lst[r];
        #pragma unroll
        for (int ni = 0; ni < NF; ni++) {
          int n = nt * BN + wn * (BN / WN) + ni * 16 + cn;
          float v = acc[mi][ni][reg] + bias[(size_t)e * N + n];
          if constexpr (GELU) {
            v = 0.5f * v * (1.0f + erff(v * 0.70710678118654752f));  // exact gelu
            ((unsigned short*)Out)[(size_t)aid * N + n] = f2bf(v);
          } else {
            ((float*)Out)[(size_t)aid * N + n] = v;
          }
        }
      }
    }
  }
}

// ---------------- combine top-2 rows (+ fused aux-loss finalize) ----------------
__global__ void k_combine(const float* __restrict__ buf, const float* __restrict__ topw,
                          float* __restrict__ out,
                          const int* __restrict__ cnt1, const float* __restrict__ psum,
                          const float* __restrict__ sqsum) {
  int i = blockIdx.x * 256 + threadIdx.x;          // per float4, NTOK*DDIM/4 total
  int t = i >> 8, c = i & 255;                     // DDIM/4 = 256
  float w0 = topw[2*t], w1 = topw[2*t + 1];
  float4 a = ((const float4*)(buf + (size_t)(2*t) * DDIM))[c];
  float4 b = ((const float4*)(buf + (size_t)(2*t + 1) * DDIM))[c];
  float4 o;
  o.x = w0*a.x + w1*b.x; o.y = w0*a.y + w1*b.y;
  o.z = w0*a.z + w1*b.z; o.w = w0*a.w + w1*b.w;
  ((float4*)out)[i] = o;
  if (i == 0) {
    float s = 0.f;
    for (int e = 0; e < NEXP; e++)
      s += ((float)cnt1[e] / (float)NTOK) * (psum[e] / (float)NTOK);
    out[(size_t)NTOK * DDIM] = (float)NEXP * s + (*sqsum) / (float)(NTOK * NEXP) * 1e-3f;
  }
}

extern "C" void kernel_launch(void* const* d_in, const int* in_sizes, int n_in,
                              void* d_out, int out_size, void* d_ws, size_t ws_size,
                              hipStream_t stream) {
  const float* x  = (const float*)d_in[0];
  const float* gw = (const float*)d_in[1];
  const float* w1 = (const float*)d_in[2];
  const float* b1 = (const float*)d_in[3];
  const float* w2 = (const float*)d_in[4];
  const float* b2 = (const float*)d_in[5];
  float* out = (float*)d_out;
  char* p = (char*)d_ws;

  // workspace layout (~136 MB)
  int*   ecnt  = (int*)p;                    // [8]
  int*   cnt1  = (int*)(p + 32);             // [8]
  float* psum  = (float*)(p + 64);           // [8]
  float* sqsum = (float*)(p + 96);           // [1]
  float* topw  = (float*)(p + 256);                            // 32 KB
  int*   elist = (int*)(p + 256 + 32768);                      // 128 KB
  unsigned short* xb  = (unsigned short*)(p + 256 + 32768 + 131072);   // 8 MB
  unsigned short* w1t = xb  + (size_t)NTOK * DDIM;                     // 32 MB  [E][F][D]
  unsigned short* w2t = w1t + (size_t)NEXP * DDIM * FDIM;              // 32 MB  [E][D][F]
  unsigned short* Hb  = w2t + (size_t)NEXP * DDIM * FDIM;              // 32 MB  [8192][F]
  float* obuf = (float*)(Hb + (size_t)NTOK * 2 * FDIM);                // 32 MB  [8192][D]

  hipMemsetAsync(p, 0, 128, stream);
  // fused prep: both weight transposes + router run concurrently (8320 blocks)
  k_prep<<<8192 + NTOK / RTOK, 256, 0, stream>>>(x, gw, w1, w2, xb, w1t, w2t,
                                                 topw, elist, ecnt, cnt1, psum, sqsum);
  // 1D swizzled grids: GEMM1 16nt*16mt*8e=2048 blocks; GEMM2 8nt*16mt*8e=1024 blocks
  k_gemm<DDIM, FDIM, true,  true ><<<(FDIM/128)*MT*NEXP, 512, 0, stream>>>(xb, w1t, b1, Hb, elist, ecnt);
  k_gemm<FDIM, DDIM, false, false><<<(DDIM/128)*MT*NEXP, 512, 0, stream>>>(Hb, w2t, b2, obuf, elist, ecnt);
  k_combine<<<NTOK * DDIM / 4 / 256, 256, 0, stream>>>(obuf, topw, out, cnt1, psum, sqsum);
}